// Round 1
// baseline (933.820 us; speedup 1.0000x reference)
//
#include <hip/hip_runtime.h>
#include <hip/hip_bf16.h>
#include <stdint.h>
#include <stddef.h>

#define SEQ 2048
#define BATCH 16
#define HID 1024
#define MM (SEQ*BATCH)   // 32768 rows
#define NN (3*HID)       // 3072 cols
#define KK HID           // 1024

typedef __bf16 bf16x8 __attribute__((ext_vector_type(8)));
typedef float floatx4 __attribute__((ext_vector_type(4)));

// ---------------- U element helpers (fp32 preferred, bf16 fallback) ----------
template <typename UT> __device__ inline void storeU(UT* p, float v);
template <> __device__ inline void storeU<float>(float* p, float v) { *p = v; }
template <> __device__ inline void storeU<__bf16>(__bf16* p, float v) { *p = (__bf16)v; }
template <typename UT> __device__ inline float loadU(const UT* p);
template <> __device__ inline float loadU<float>(const float* p) { return *p; }
template <> __device__ inline float loadU<__bf16>(const __bf16* p) { return (float)*p; }

// ---------------- cast input fp32 -> bf16 (Ap[M][K] row-major) ---------------
__global__ __launch_bounds__(256) void cast_a_kernel(const float* __restrict__ in,
                                                     __bf16* __restrict__ out) {
  size_t i = (size_t)blockIdx.x * 256 + threadIdx.x;   // one float4 per thread
  float4 v = ((const float4*)in)[i];
  typedef __bf16 bf16x4 __attribute__((ext_vector_type(4)));
  bf16x4 o;
  o[0] = (__bf16)v.x; o[1] = (__bf16)v.y; o[2] = (__bf16)v.z; o[3] = (__bf16)v.w;
  ((bf16x4*)out)[i] = o;
}

// ------------- transpose+cast weight [K][N] fp32 -> Wp [N][K] bf16 -----------
__global__ __launch_bounds__(256) void pack_w_kernel(const float* __restrict__ w,
                                                     __bf16* __restrict__ wp) {
  __shared__ float tile[32][33];
  int n0 = blockIdx.x * 32, k0 = blockIdx.y * 32;
  int tx = threadIdx.x, ty = threadIdx.y;   // 32 x 8
#pragma unroll
  for (int r = 0; r < 4; r++)
    tile[ty + 8*r][tx] = w[(size_t)(k0 + ty + 8*r) * NN + n0 + tx];
  __syncthreads();
#pragma unroll
  for (int r = 0; r < 4; r++)
    wp[(size_t)(n0 + ty + 8*r) * KK + k0 + tx] = (__bf16)tile[tx][ty + 8*r];
}

// ---------------- GEMM: U[row][n] = sum_k Ap[row][k] * Wp[n][k] --------------
// 128x128 tile, BK=64, 256 thr (4 waves 2x2, 64x64 each), 16x16x32 bf16 MFMA.
// LDS staged via global_load_lds(16B); XOR swizzle done on the global side:
// stored chunk index = row*8 + (kc ^ (row&7))  -> max 2-way bank alias (free).
template <typename UT>
__global__ __launch_bounds__(256) void gemm_kernel(const __bf16* __restrict__ A,
                                                   const __bf16* __restrict__ B,
                                                   UT* __restrict__ U) {
  __shared__ __align__(16) char smem[32768];   // A tile 16KB | B tile 16KB
  const int tid  = threadIdx.x;
  const int lane = tid & 63;
  const int wave = tid >> 6;
  const int tileN = blockIdx.x * 128;
  const int tileM = blockIdx.y * 128;

  // staging sources: slot s = j*256+tid ; s<1024 -> A chunk, else B chunk
  const char* gsrc[8];
  uint32_t    ldsoff[8];
#pragma unroll
  for (int j = 0; j < 8; j++) {
    int s   = j * 256 + tid;
    int isB = s >> 10;
    int s2  = s & 1023;
    int row = s2 >> 3;
    int cs  = s2 & 7;
    int kc  = cs ^ (row & 7);
    const __bf16* base = isB ? (B + (size_t)(tileN + row) * KK)
                             : (A + (size_t)(tileM + row) * KK);
    gsrc[j]   = (const char*)(base + kc * 8);
    ldsoff[j] = (uint32_t)(j * 4096 + wave * 1024);   // wave-uniform
  }

  const int wm = (wave >> 1) * 64;
  const int wn = (wave & 1) * 64;
  const int g  = lane >> 4;

  uint32_t aoff[4], boff[4];
#pragma unroll
  for (int i = 0; i < 4; i++) {
    int row  = wm + i * 16 + (lane & 15);
    aoff[i]  = (uint32_t)((row * 8 + (g ^ (row & 7))) * 16);
    int nrow = wn + i * 16 + (lane & 15);
    boff[i]  = (uint32_t)(16384 + (nrow * 8 + (g ^ (nrow & 7))) * 16);
  }

  floatx4 acc[4][4];
#pragma unroll
  for (int mi = 0; mi < 4; mi++)
#pragma unroll
    for (int ni = 0; ni < 4; ni++) acc[mi][ni] = (floatx4)0.0f;

  for (int it = 0; it < KK / 64; ++it) {
    __syncthreads();                 // prev compute done before overwrite
#pragma unroll
    for (int j = 0; j < 8; j++)
      __builtin_amdgcn_global_load_lds(
          (const __attribute__((address_space(1))) void*)(gsrc[j]),
          (__attribute__((address_space(3))) void*)(smem + ldsoff[j]), 16, 0, 0);
#pragma unroll
    for (int j = 0; j < 8; j++) gsrc[j] += 128;   // advance 64 bf16
    __syncthreads();                 // compiler drains vmcnt before barrier

#pragma unroll
    for (int ks = 0; ks < 2; ++ks) {
      bf16x8 a[4], b[4];
#pragma unroll
      for (int i = 0; i < 4; i++) {
        a[i] = *(const bf16x8*)(smem + (aoff[i] ^ (ks * 64)));
        b[i] = *(const bf16x8*)(smem + (boff[i] ^ (ks * 64)));
      }
#pragma unroll
      for (int mi = 0; mi < 4; mi++)
#pragma unroll
        for (int ni = 0; ni < 4; ni++)
          acc[mi][ni] = __builtin_amdgcn_mfma_f32_16x16x32_bf16(
              a[mi], b[ni], acc[mi][ni], 0, 0, 0);
    }
  }

  // epilogue: C/D layout col=lane&15, row=(lane>>4)*4+reg
  const int r0 = (lane >> 4) * 4;
  const int cc = lane & 15;
#pragma unroll
  for (int mi = 0; mi < 4; mi++)
#pragma unroll
    for (int ni = 0; ni < 4; ni++) {
      int col = tileN + wn + ni * 16 + cc;
#pragma unroll
      for (int r = 0; r < 4; r++) {
        int row = tileM + wm + mi * 16 + r0 + r;
        storeU(&U[(size_t)row * NN + col], acc[mi][ni][r]);
      }
    }
}

// ---------------- sequential SRU scan ----------------------------------------
__device__ inline float sigmoidf_fast(float z) {
  return __builtin_amdgcn_rcpf(1.0f + __expf(-z));
}

template <typename UT>
__global__ __launch_bounds__(256) void scan_kernel(const UT* __restrict__ U,
                                                   const float* __restrict__ x,
                                                   const float* __restrict__ bias,
                                                   float* __restrict__ out) {
  int idx = blockIdx.x * 256 + threadIdx.x;   // 0..16383 over (b,h)
  int b = idx >> 10, h = idx & 1023;
  float b0 = bias[h], b1 = bias[HID + h];

  const UT*    up = U + (size_t)b * NN + 3 * h;   // step stride BATCH*NN
  const float* xp = x + idx;                      // step stride BATCH*HID
  float* Hout = out + idx;
  float* Cout = out + (size_t)SEQ * BATCH * HID + idx;

  constexpr int P = 16;
  float pu0[P], pu1[P], pu2[P], px[P];
#pragma unroll
  for (int i = 0; i < P; i++) {
    const UT* u = up + (size_t)i * (BATCH * NN);
    pu0[i] = loadU(u); pu1[i] = loadU(u + 1); pu2[i] = loadU(u + 2);
    px[i]  = xp[(size_t)i * (BATCH * HID)];
  }

  float c = 0.0f;
  int tt = 0;
  for (; tt < SEQ - P; tt += P) {
#pragma unroll
    for (int i = 0; i < P; i++) {
      int t = tt + i;
      float u0 = pu0[i], u1 = pu1[i], u2 = pu2[i], xv = px[i];
      // prefetch t+P
      const UT* u = up + (size_t)(t + P) * (BATCH * NN);
      pu0[i] = loadU(u); pu1[i] = loadU(u + 1); pu2[i] = loadU(u + 2);
      px[i]  = xp[(size_t)(t + P) * (BATCH * HID)];

      float f = sigmoidf_fast(u0 + b0 * c + b0);
      float r = sigmoidf_fast(u1 + b1 * c + b1);
      c = f * c + (1.0f - f) * u2;
      float ht = r * c + (1.0f - r) * xv;
      Cout[(size_t)t * (BATCH * HID)] = c;
      Hout[(size_t)t * (BATCH * HID)] = ht;
    }
  }
  // tail (no prefetch)
#pragma unroll
  for (int i = 0; i < P; i++) {
    int t = tt + i;
    float f = sigmoidf_fast(pu0[i] + b0 * c + b0);
    float r = sigmoidf_fast(pu1[i] + b1 * c + b1);
    c = f * c + (1.0f - f) * pu2[i];
    float ht = r * c + (1.0f - r) * px[i];
    Cout[(size_t)t * (BATCH * HID)] = c;
    Hout[(size_t)t * (BATCH * HID)] = ht;
  }
}

// ---------------- launch ------------------------------------------------------
extern "C" void kernel_launch(void* const* d_in, const int* in_sizes, int n_in,
                              void* d_out, int out_size, void* d_ws, size_t ws_size,
                              hipStream_t stream) {
  const float* input  = (const float*)d_in[0];
  const float* weight = (const float*)d_in[1];
  const float* bias   = (const float*)d_in[2];
  float* out = (float*)d_out;

  char* ws = (char*)d_ws;
  const size_t apB = (size_t)MM * KK * 2;   // 64 MiB
  const size_t wpB = (size_t)NN * KK * 2;   // 6 MiB
  const size_t uF  = (size_t)MM * NN * 4;   // 384 MiB fp32 U
  bool useF32 = ws_size >= uF + apB + wpB;
  size_t uB = useF32 ? uF : uF / 2;

  void*   Uv = (void*)ws;
  __bf16* Ap = (__bf16*)(ws + uB);
  __bf16* Wp = (__bf16*)(ws + uB + apB);

  cast_a_kernel<<<(MM * KK) / 4 / 256, 256, 0, stream>>>(input, Ap);
  pack_w_kernel<<<dim3(NN / 32, KK / 32), dim3(32, 8), 0, stream>>>(weight, Wp);

  if (useF32) {
    gemm_kernel<float><<<dim3(NN / 128, MM / 128), 256, 0, stream>>>(Ap, Wp, (float*)Uv);
    scan_kernel<float><<<(BATCH * HID) / 256, 256, 0, stream>>>((const float*)Uv, input, bias, out);
  } else {
    gemm_kernel<__bf16><<<dim3(NN / 128, MM / 128), 256, 0, stream>>>(Ap, Wp, (__bf16*)Uv);
    scan_kernel<__bf16><<<(BATCH * HID) / 256, 256, 0, stream>>>((const __bf16*)Uv, input, bias, out);
  }
}

// Round 2
// 845.075 us; speedup vs baseline: 1.1050x; 1.1050x over previous
//
#include <hip/hip_runtime.h>
#include <hip/hip_bf16.h>
#include <stdint.h>
#include <stddef.h>

#define SEQ 2048
#define BATCH 16
#define HID 1024
#define MM (SEQ*BATCH)   // 32768 rows
#define NN (3*HID)       // 3072 cols
#define KK HID           // 1024

typedef __bf16 bf16x8 __attribute__((ext_vector_type(8)));
typedef float floatx4 __attribute__((ext_vector_type(4)));

// ---------------- U element helpers (fp32 preferred, bf16 fallback) ----------
template <typename UT> __device__ inline void storeU(UT* p, float v);
template <> __device__ inline void storeU<float>(float* p, float v) { *p = v; }
template <> __device__ inline void storeU<__bf16>(__bf16* p, float v) { *p = (__bf16)v; }
template <typename UT> __device__ inline float loadU(const UT* p);
template <> __device__ inline float loadU<float>(const float* p) { return *p; }
template <> __device__ inline float loadU<__bf16>(const __bf16* p) { return (float)*p; }

// ---------------- cast input fp32 -> bf16 (Ap[M][K] row-major) ---------------
__global__ __launch_bounds__(256) void cast_a_kernel(const float* __restrict__ in,
                                                     __bf16* __restrict__ out) {
  size_t i = (size_t)blockIdx.x * 256 + threadIdx.x;   // one float4 per thread
  float4 v = ((const float4*)in)[i];
  typedef __bf16 bf16x4 __attribute__((ext_vector_type(4)));
  bf16x4 o;
  o[0] = (__bf16)v.x; o[1] = (__bf16)v.y; o[2] = (__bf16)v.z; o[3] = (__bf16)v.w;
  ((bf16x4*)out)[i] = o;
}

// ------------- transpose+cast weight [K][N] fp32 -> Wp [N][K] bf16 -----------
__global__ __launch_bounds__(256) void pack_w_kernel(const float* __restrict__ w,
                                                     __bf16* __restrict__ wp) {
  __shared__ float tile[32][33];
  int n0 = blockIdx.x * 32, k0 = blockIdx.y * 32;
  int tx = threadIdx.x, ty = threadIdx.y;   // 32 x 8
#pragma unroll
  for (int r = 0; r < 4; r++)
    tile[ty + 8*r][tx] = w[(size_t)(k0 + ty + 8*r) * NN + n0 + tx];
  __syncthreads();
#pragma unroll
  for (int r = 0; r < 4; r++)
    wp[(size_t)(n0 + ty + 8*r) * KK + k0 + tx] = (__bf16)tile[tx][ty + 8*r];
}

// ---------------- GEMM: U[row][n] = sum_k Ap[row][k] * Wp[n][k] --------------
// 128x128 tile, BK=64, 256 thr (4 waves 2x2, 64x64 each), 16x16x32 bf16 MFMA.
// LDS staged via global_load_lds(16B); XOR swizzle done on the global side:
// stored chunk index = row*8 + (kc ^ (row&7))  -> max 2-way bank alias (free).
template <typename UT>
__global__ __launch_bounds__(256) void gemm_kernel(const __bf16* __restrict__ A,
                                                   const __bf16* __restrict__ B,
                                                   UT* __restrict__ U) {
  __shared__ __align__(16) char smem[32768];   // A tile 16KB | B tile 16KB
  const int tid  = threadIdx.x;
  const int lane = tid & 63;
  const int wave = tid >> 6;
  const int tileN = blockIdx.x * 128;
  const int tileM = blockIdx.y * 128;

  // staging sources: slot s = j*256+tid ; s<1024 -> A chunk, else B chunk
  const char* gsrc[8];
  uint32_t    ldsoff[8];
#pragma unroll
  for (int j = 0; j < 8; j++) {
    int s   = j * 256 + tid;
    int isB = s >> 10;
    int s2  = s & 1023;
    int row = s2 >> 3;
    int cs  = s2 & 7;
    int kc  = cs ^ (row & 7);
    const __bf16* base = isB ? (B + (size_t)(tileN + row) * KK)
                             : (A + (size_t)(tileM + row) * KK);
    gsrc[j]   = (const char*)(base + kc * 8);
    ldsoff[j] = (uint32_t)(j * 4096 + wave * 1024);   // wave-uniform
  }

  const int wm = (wave >> 1) * 64;
  const int wn = (wave & 1) * 64;
  const int g  = lane >> 4;

  uint32_t aoff[4], boff[4];
#pragma unroll
  for (int i = 0; i < 4; i++) {
    int row  = wm + i * 16 + (lane & 15);
    aoff[i]  = (uint32_t)((row * 8 + (g ^ (row & 7))) * 16);
    int nrow = wn + i * 16 + (lane & 15);
    boff[i]  = (uint32_t)(16384 + (nrow * 8 + (g ^ (nrow & 7))) * 16);
  }

  floatx4 acc[4][4];
#pragma unroll
  for (int mi = 0; mi < 4; mi++)
#pragma unroll
    for (int ni = 0; ni < 4; ni++) acc[mi][ni] = (floatx4)0.0f;

  for (int it = 0; it < KK / 64; ++it) {
    __syncthreads();                 // prev compute done before overwrite
#pragma unroll
    for (int j = 0; j < 8; j++)
      __builtin_amdgcn_global_load_lds(
          (const __attribute__((address_space(1))) void*)(gsrc[j]),
          (__attribute__((address_space(3))) void*)(smem + ldsoff[j]), 16, 0, 0);
#pragma unroll
    for (int j = 0; j < 8; j++) gsrc[j] += 128;   // advance 64 bf16
    __syncthreads();                 // compiler drains vmcnt before barrier

#pragma unroll
    for (int ks = 0; ks < 2; ++ks) {
      bf16x8 a[4], b[4];
#pragma unroll
      for (int i = 0; i < 4; i++) {
        a[i] = *(const bf16x8*)(smem + (aoff[i] ^ (ks * 64)));
        b[i] = *(const bf16x8*)(smem + (boff[i] ^ (ks * 64)));
      }
#pragma unroll
      for (int mi = 0; mi < 4; mi++)
#pragma unroll
        for (int ni = 0; ni < 4; ni++)
          acc[mi][ni] = __builtin_amdgcn_mfma_f32_16x16x32_bf16(
              a[mi], b[ni], acc[mi][ni], 0, 0, 0);
    }
  }

  // epilogue: C/D layout col=lane&15, row=(lane>>4)*4+reg
  const int r0 = (lane >> 4) * 4;
  const int cc = lane & 15;
#pragma unroll
  for (int mi = 0; mi < 4; mi++)
#pragma unroll
    for (int ni = 0; ni < 4; ni++) {
      int col = tileN + wn + ni * 16 + cc;
#pragma unroll
      for (int r = 0; r < 4; r++) {
        int row = tileM + wm + mi * 16 + r0 + r;
        storeU(&U[(size_t)row * NN + col], acc[mi][ni][r]);
      }
    }
}

// ---------------- sequential SRU scan ----------------------------------------
// 256 blocks x 64 threads: one wave per block so all 256 CUs issue memory
// traffic. (R1: 64 blocks x 256 -> only 64 CUs active -> 1.6 TB/s, exactly the
// 64-CU per-CU load ceiling. Same total waves; spread is what matters.)
__device__ inline float sigmoidf_fast(float z) {
  return __builtin_amdgcn_rcpf(1.0f + __expf(-z));
}

template <typename UT>
__global__ __launch_bounds__(64) void scan_kernel(const UT* __restrict__ U,
                                                  const float* __restrict__ x,
                                                  const float* __restrict__ bias,
                                                  float* __restrict__ out) {
  int idx = blockIdx.x * 64 + threadIdx.x;   // 0..16383 over (b,h)
  int b = idx >> 10, h = idx & 1023;
  float b0 = bias[h], b1 = bias[HID + h];

  const UT*    up = U + (size_t)b * NN + 3 * h;   // step stride BATCH*NN
  const float* xp = x + idx;                      // step stride BATCH*HID
  float* Hout = out + idx;
  float* Cout = out + (size_t)SEQ * BATCH * HID + idx;

  constexpr int P = 16;
  float pu0[P], pu1[P], pu2[P], px[P];
#pragma unroll
  for (int i = 0; i < P; i++) {
    const UT* u = up + (size_t)i * (BATCH * NN);
    pu0[i] = loadU(u); pu1[i] = loadU(u + 1); pu2[i] = loadU(u + 2);
    px[i]  = xp[(size_t)i * (BATCH * HID)];
  }

  float c = 0.0f;
  int tt = 0;
  for (; tt < SEQ - P; tt += P) {
#pragma unroll
    for (int i = 0; i < P; i++) {
      int t = tt + i;
      float u0 = pu0[i], u1 = pu1[i], u2 = pu2[i], xv = px[i];
      // prefetch t+P
      const UT* u = up + (size_t)(t + P) * (BATCH * NN);
      pu0[i] = loadU(u); pu1[i] = loadU(u + 1); pu2[i] = loadU(u + 2);
      px[i]  = xp[(size_t)(t + P) * (BATCH * HID)];

      float f = sigmoidf_fast(u0 + b0 * c + b0);
      float r = sigmoidf_fast(u1 + b1 * c + b1);
      c = f * c + (1.0f - f) * u2;
      float ht = r * c + (1.0f - r) * xv;
      Cout[(size_t)t * (BATCH * HID)] = c;
      Hout[(size_t)t * (BATCH * HID)] = ht;
    }
  }
  // tail (no prefetch)
#pragma unroll
  for (int i = 0; i < P; i++) {
    int t = tt + i;
    float f = sigmoidf_fast(pu0[i] + b0 * c + b0);
    float r = sigmoidf_fast(pu1[i] + b1 * c + b1);
    c = f * c + (1.0f - f) * pu2[i];
    float ht = r * c + (1.0f - r) * px[i];
    Cout[(size_t)t * (BATCH * HID)] = c;
    Hout[(size_t)t * (BATCH * HID)] = ht;
  }
}

// ---------------- launch ------------------------------------------------------
extern "C" void kernel_launch(void* const* d_in, const int* in_sizes, int n_in,
                              void* d_out, int out_size, void* d_ws, size_t ws_size,
                              hipStream_t stream) {
  const float* input  = (const float*)d_in[0];
  const float* weight = (const float*)d_in[1];
  const float* bias   = (const float*)d_in[2];
  float* out = (float*)d_out;

  char* ws = (char*)d_ws;
  const size_t apB = (size_t)MM * KK * 2;   // 64 MiB
  const size_t wpB = (size_t)NN * KK * 2;   // 6 MiB
  const size_t uF  = (size_t)MM * NN * 4;   // 384 MiB fp32 U
  bool useF32 = ws_size >= uF + apB + wpB;
  size_t uB = useF32 ? uF : uF / 2;

  void*   Uv = (void*)ws;
  __bf16* Ap = (__bf16*)(ws + uB);
  __bf16* Wp = (__bf16*)(ws + uB + apB);

  cast_a_kernel<<<(MM * KK) / 4 / 256, 256, 0, stream>>>(input, Ap);
  pack_w_kernel<<<dim3(NN / 32, KK / 32), dim3(32, 8), 0, stream>>>(weight, Wp);

  if (useF32) {
    gemm_kernel<float><<<dim3(NN / 128, MM / 128), 256, 0, stream>>>(Ap, Wp, (float*)Uv);
    scan_kernel<float><<<(BATCH * HID) / 64, 64, 0, stream>>>((const float*)Uv, input, bias, out);
  } else {
    gemm_kernel<__bf16><<<dim3(NN / 128, MM / 128), 256, 0, stream>>>(Ap, Wp, (__bf16*)Uv);
    scan_kernel<__bf16><<<(BATCH * HID) / 64, 64, 0, stream>>>((const __bf16*)Uv, input, bias, out);
  }
}